// Round 7
// baseline (353.678 us; speedup 1.0000x reference)
//
#include <hip/hip_runtime.h>
#include <hip/hip_fp16.h>
#include <hip/hip_cooperative_groups.h>
#include <cstdint>

namespace cg = cooperative_groups;

// R19: fuse gather2 INTO sort_gather1 via cooperative grid sync.
// The sorted edge list B[] is already in LDS per-bucket when sp is written;
// gather2 only needs a global barrier (sp of all buckets). this_grid().sync()
// provides it -> pong write (12.8MB) + pong read (12.8MB) + rowptr/cnt
// re-reads + one launch all deleted. Co-residency: 61KB LDS -> 2 blk/CU ->
// 512 slots >= NB<=512 (guarded). Fallback to split kernels (with pong) if
// cooperative launch errors. Distinct from R8-R10 mega-fusion regressions:
// same-geometry same-block-mapping fusion with LDS reuse, single sync.
// Session evidence: R12 197; R13 610; R14 296; R15 182.1; R16 189.3
// (PT4096 -3.5 + merge@256thr); R17 185.8; R18 178.3 (merge@1024thr).

#define F_IN 128
#define F_HID 16
#define PB 1024           // partition / deg_gemm1 / fused block threads
#define PT 8192           // edges per partition tile
#define NBMAX 512         // max buckets (nodes/256), n <= 131072
#define CAPMAX 15104      // max bucket capacity (LDS B[capB] must fit 64KB)

// ===========================================================================
// Phase 1: counting-sort partition into 256-node dst buckets (R15-exact).
// Packed edge word: r | (c&255)<<17  (needs n <= 2^17). int4 edge loads.
// ===========================================================================
__global__ __launch_bounds__(PB) void partition_kernel(
    const int* __restrict__ row, const int* __restrict__ col,
    int* __restrict__ cursor,        // [NBMAX], zeroed
    int* __restrict__ ping,          // [NB * capB]
    int capB, int NB, int n_edges) {
    __shared__ int sh_hist[NBMAX];
    __shared__ int sh_scan[NBMAX];
    __shared__ int sh_cur[NBMAX];
    __shared__ int sh_base[NBMAX];
    __shared__ int sh_wsum[16];
    __shared__ int sh_packed[PT];
    __shared__ unsigned short sh_bkt[PT];

    int t = threadIdx.x;
    int lane = t & 63;
    int wv = t >> 6;
    int ntiles = (n_edges + PT - 1) / PT;
    bool vec_ok = ((n_edges & 3) == 0);   // col = row + n_edges 16B-aligned

    for (int tile = blockIdx.x; tile < ntiles; tile += gridDim.x) {
        int tbase = tile * PT;
        int tcnt = min(PT, n_edges - tbase);

        if (t < NBMAX) sh_hist[t] = 0;
        __syncthreads();

        int e0 = tbase + t * 8;
        int pk[8], bb[8];
        if (vec_ok && e0 + 8 <= n_edges) {
            int4 a0 = *(const int4*)(row + e0);
            int4 a1 = *(const int4*)(row + e0 + 4);
            int4 c0 = *(const int4*)(col + e0);
            int4 c1 = *(const int4*)(col + e0 + 4);
            int rr[8] = {a0.x, a0.y, a0.z, a0.w, a1.x, a1.y, a1.z, a1.w};
            int cc[8] = {c0.x, c0.y, c0.z, c0.w, c1.x, c1.y, c1.z, c1.w};
#pragma unroll
            for (int k = 0; k < 8; k++) {
                bb[k] = cc[k] >> 8;
                pk[k] = rr[k] | ((cc[k] & 255) << 17);
                atomicAdd(&sh_hist[bb[k]], 1);
            }
        } else {
#pragma unroll
            for (int k = 0; k < 8; k++) {
                int e = e0 + k;
                bb[k] = -1;
                if (e < n_edges) {
                    int r = row[e];
                    int c = col[e];
                    bb[k] = c >> 8;
                    pk[k] = r | ((c & 255) << 17);
                    atomicAdd(&sh_hist[bb[k]], 1);
                }
            }
        }
        __syncthreads();

        // wave-hierarchical inclusive scan of sh_hist[0..511]
        {
            int v = (t < NBMAX) ? sh_hist[t] : 0;
            int incl = v;
#pragma unroll
            for (int off = 1; off < 64; off <<= 1) {
                int u = __shfl_up(incl, off, 64);
                if (lane >= off) incl += u;
            }
            if (lane == 63) sh_wsum[wv] = incl;
            __syncthreads();
            if (t < 16) {
                int s = sh_wsum[t];
#pragma unroll
                for (int off = 1; off < 16; off <<= 1) {
                    int u = __shfl_up(s, off, 16);
                    if (t >= off) s += u;
                }
                sh_wsum[t] = s;
            }
            __syncthreads();
            int wexcl = (wv > 0) ? sh_wsum[wv - 1] : 0;
            if (t < NBMAX) sh_scan[t] = incl + wexcl;
        }
        __syncthreads();

        if (t < NBMAX) {
            int h = sh_hist[t];
            sh_cur[t] = sh_scan[t] - h;
            sh_base[t] = (h > 0 && t < NB) ? atomicAdd(&cursor[t], h) : 0;
        }
        __syncthreads();

        // LDS reorder scatter
#pragma unroll
        for (int k = 0; k < 8; k++) {
            if (bb[k] >= 0) {
                int p = atomicAdd(&sh_cur[bb[k]], 1);
                sh_packed[p] = pk[k];
                sh_bkt[p] = (unsigned short)bb[k];
            }
        }
        __syncthreads();

        // write runs out bucket-contiguously
#pragma unroll
        for (int k = 0; k < 8; k++) {
            int p = t + k * PB;
            if (p < tcnt) {
                int b = sh_bkt[p];
                int off = p - (sh_scan[b] - sh_hist[b]);
                int gp = sh_base[b] + off;
                if (gp < capB) ping[(size_t)b * capB + gp] = sh_packed[p];
            }
        }
        __syncthreads();
    }
}

// ===========================================================================
// Phase 2 (merged, 1024 thr): per-bucket degree histogram (phase A, full
// block) + gemm1 (phase B, j-split: 4 threads/node, 4 outputs each).
// Block b's node range [256b, 256b+256) == bucket b's range.
// h1p = fp16( (x @ W1) * dinv[node] ), cnt/rowptr written for later kernels.
// ===========================================================================
__global__ __launch_bounds__(PB) void deg_gemm1_kernel(
    const int* __restrict__ cursor, const int* __restrict__ ping,
    const float* __restrict__ x, const float* __restrict__ W1,
    int* __restrict__ cnt, int* __restrict__ rowptr,
    __half* __restrict__ h1p, int capB, int n) {
    __shared__ float sW[F_IN * F_HID];
    __shared__ int hist[256];
    __shared__ int wsum[4];

    int b = blockIdx.x, t = threadIdx.x;
    int lane = t & 63;
    int wv = t >> 6;

    // weight staging (barrier below covers it)
    for (int i = t; i < F_IN * F_HID; i += PB) sW[i] = W1[i];
    if (t < 256) hist[t] = 0;
    __syncthreads();

    // phase A: histogram bucket edges by sub-index (node within bucket)
    int cb = min(cursor[b], capB);
    const int* src = ping + (size_t)b * capB;
    for (int i = t; i < cb; i += PB) {
        atomicAdd(&hist[(src[i] >> 17) & 255], 1);
    }
    __syncthreads();

    // inclusive scan of hist[0..255] (first 4 waves carry data)
    {
        int h = (t < 256) ? hist[t] : 0;
        int incl = h;
#pragma unroll
        for (int off = 1; off < 64; off <<= 1) {
            int u = __shfl_up(incl, off, 64);
            if (lane >= off) incl += u;
        }
        if (t < 256 && lane == 63) wsum[wv] = incl;
        __syncthreads();
        if (t < 4) {
            int s = wsum[t];
#pragma unroll
            for (int off = 1; off < 4; off <<= 1) {
                int u = __shfl_up(s, off, 4);
                if (t >= off) s += u;
            }
            wsum[t] = s;
        }
        __syncthreads();
        if (t < 256) {
            int g = b * 256 + t;
            if (g < n) {
                int wexcl = (wv > 0) ? wsum[wv - 1] : 0;
                cnt[g] = h;
                rowptr[g] = b * capB + (incl + wexcl - h);
            }
        }
    }
    // hist[] untouched by scan -> safe to read below without extra barrier

    // phase B: gemm1, 4 threads per node, 4 output features each
    int sub = t >> 2;
    int node = b * 256 + sub;
    if (node >= n) return;
    int jq = (t & 3) * 4;

    const float4* xr = (const float4*)(x + (size_t)node * F_IN);
    float a0 = 0.0f, a1 = 0.0f, a2 = 0.0f, a3 = 0.0f;

#pragma unroll 4
    for (int k4 = 0; k4 < F_IN / 4; k4++) {
        float4 xv = xr[k4];
        const float* w0 = &sW[(k4 * 4 + 0) * F_HID + jq];
        const float* w1 = &sW[(k4 * 4 + 1) * F_HID + jq];
        const float* w2 = &sW[(k4 * 4 + 2) * F_HID + jq];
        const float* w3 = &sW[(k4 * 4 + 3) * F_HID + jq];
        a0 += xv.x * w0[0] + xv.y * w1[0] + xv.z * w2[0] + xv.w * w3[0];
        a1 += xv.x * w0[1] + xv.y * w1[1] + xv.z * w2[1] + xv.w * w3[1];
        a2 += xv.x * w0[2] + xv.y * w1[2] + xv.z * w2[2] + xv.w * w3[2];
        a3 += xv.x * w0[3] + xv.y * w1[3] + xv.z * w2[3] + xv.w * w3[3];
    }

    float d = rsqrtf((float)hist[sub] + 1.0f);
    __half2 hv[2];
    hv[0] = __floats2half2_rn(a0 * d, a1 * d);
    hv[1] = __floats2half2_rn(a2 * d, a3 * d);
    *(float2*)(h1p + (size_t)node * F_HID + jq) = *(float2*)&hv[0];
}

// ===========================================================================
// Phase 3+4 FUSED (cooperative): per-bucket counting sort (LDS) + layer-1
// windowed gather -> sp, grid.sync(), layer-2 windowed gather from the SAME
// LDS B[] -> out. No pong, no extra launch. All threads reach the sync.
// ===========================================================================
__global__ __launch_bounds__(PB) void sort_gather12(
    const int* __restrict__ cursor, const int* __restrict__ ping,
    const int* __restrict__ cnt, const int* __restrict__ rowptr,
    const __half* __restrict__ h1p, const float* __restrict__ b1,
    const float* __restrict__ W2, float* __restrict__ sp,
    const float* __restrict__ b2, float* __restrict__ out,
    int capB, int n) {
    extern __shared__ int B[];        // capB ints (sorted edge srcs)
    __shared__ int s_excl[256];
    __shared__ int s_h[256];
    __shared__ int cur[256];

    int b = blockIdx.x, t = threadIdx.x;

    if (t < 256) {
        int g = b * 256 + t;
        int h = (g < n) ? cnt[g] : 0;
        int excl = (g < n) ? (rowptr[g] - b * capB) : 0;
        s_h[t] = h;
        s_excl[t] = excl;
        cur[t] = excl;
    }
    __syncthreads();

    int cb = min(cursor[b], capB);
    const int* src = ping + (size_t)b * capB;

    // counting scatter into LDS (ping is L2/L3-hot)
    for (int i = t; i < cb; i += PB) {
        int v = src[i];
        int p = atomicAdd(&cur[(v >> 17) & 255], 1);
        B[p] = v & 131071;
    }
    __syncthreads();

    // layer-1 windowed gather: 8 lanes/node, 8 independent h1p loads/window
    int l = t & 7;
    for (int j = t >> 3; j < 256; j += (PB >> 3)) {
        int g = b * 256 + j;
        if (g >= n) continue;
        int h = s_h[j];
        int base = s_excl[j];
        int end = base + h;

        float ax = 0.0f, ay = 0.0f;
        for (; base + 8 <= end; base += 8) {
#pragma unroll
            for (int m = 0; m < 8; m++) {
                int rm = B[base + m];
                float2 f = __half22float2(*(const __half2*)(h1p + (size_t)rm * F_HID + 2 * l));
                ax += f.x; ay += f.y;
            }
        }
        for (int m = 0; m < end - base; m++) {
            int rm = B[base + m];
            float2 f = __half22float2(*(const __half2*)(h1p + (size_t)rm * F_HID + 2 * l));
            ax += f.x; ay += f.y;
        }

        float dc = rsqrtf((float)h + 1.0f);
        float2 fs = __half22float2(*(const __half2*)(h1p + (size_t)g * F_HID + 2 * l));
        float v0 = (ax + fs.x) * dc + b1[2 * l];
        float v1 = (ay + fs.y) * dc + b1[2 * l + 1];
        v0 = fmaxf(v0, 0.0f);
        v1 = fmaxf(v1, 0.0f);
        float tt = v0 * W2[2 * l] + v1 * W2[2 * l + 1];  // fused [16,1] GEMM
        tt += __shfl_xor(tt, 1, 8);
        tt += __shfl_xor(tt, 2, 8);
        tt += __shfl_xor(tt, 4, 8);
        if (l == 0) sp[g] = tt * dc;   // pre-scale by src norm for layer 2
    }

    // sp of ALL buckets must be visible before layer 2
    __threadfence();
    cg::this_grid().sync();

    // layer-2 windowed gather from the SAME LDS B[]: 16 lanes/node
    int l16 = t & 15;
    for (int j = t >> 4; j < 256; j += (PB >> 4)) {
        int g = b * 256 + j;
        if (g >= n) continue;
        int h = s_h[j];
        int base = s_excl[j];
        int end = base + h;

        float acc = 0.0f;
        for (int e = base + l16; e < end; e += 16) {
            acc += sp[B[e]];
        }
        acc += __shfl_xor(acc, 1, 16);
        acc += __shfl_xor(acc, 2, 16);
        acc += __shfl_xor(acc, 4, 16);
        acc += __shfl_xor(acc, 8, 16);
        if (l16 == 0) {
            float v = (acc + sp[g]) * rsqrtf((float)h + 1.0f) + b2[0];
            out[g] = 1.0f / (1.0f + __expf(-v));
        }
    }
}

// ===========================================================================
// Split-path kernels (fallback if cooperative launch unavailable): R18-exact.
// ===========================================================================
__global__ __launch_bounds__(PB) void sort_gather1(
    const int* __restrict__ cursor, const int* __restrict__ ping,
    const int* __restrict__ cnt, const int* __restrict__ rowptr,
    const __half* __restrict__ h1p, const float* __restrict__ b1,
    const float* __restrict__ W2, float* __restrict__ sp,
    int* __restrict__ pong, int capB, int n) {
    extern __shared__ int B[];
    __shared__ int s_excl[256];
    __shared__ int s_h[256];
    __shared__ int cur[256];

    int b = blockIdx.x, t = threadIdx.x;

    if (t < 256) {
        int g = b * 256 + t;
        int h = (g < n) ? cnt[g] : 0;
        int excl = (g < n) ? (rowptr[g] - b * capB) : 0;
        s_h[t] = h;
        s_excl[t] = excl;
        cur[t] = excl;
    }
    __syncthreads();

    int cb = min(cursor[b], capB);
    const int* src = ping + (size_t)b * capB;

    for (int i = t; i < cb; i += PB) {
        int v = src[i];
        int p = atomicAdd(&cur[(v >> 17) & 255], 1);
        B[p] = v & 131071;
    }
    __syncthreads();

    for (int i = t; i < cb; i += PB) {
        pong[(size_t)b * capB + i] = B[i];
    }

    int l = t & 7;
    for (int j = t >> 3; j < 256; j += (PB >> 3)) {
        int g = b * 256 + j;
        if (g >= n) continue;
        int h = s_h[j];
        int base = s_excl[j];
        int end = base + h;

        float ax = 0.0f, ay = 0.0f;
        for (; base + 8 <= end; base += 8) {
#pragma unroll
            for (int m = 0; m < 8; m++) {
                int rm = B[base + m];
                float2 f = __half22float2(*(const __half2*)(h1p + (size_t)rm * F_HID + 2 * l));
                ax += f.x; ay += f.y;
            }
        }
        for (int m = 0; m < end - base; m++) {
            int rm = B[base + m];
            float2 f = __half22float2(*(const __half2*)(h1p + (size_t)rm * F_HID + 2 * l));
            ax += f.x; ay += f.y;
        }

        float dc = rsqrtf((float)h + 1.0f);
        float2 fs = __half22float2(*(const __half2*)(h1p + (size_t)g * F_HID + 2 * l));
        float v0 = (ax + fs.x) * dc + b1[2 * l];
        float v1 = (ay + fs.y) * dc + b1[2 * l + 1];
        v0 = fmaxf(v0, 0.0f);
        v1 = fmaxf(v1, 0.0f);
        float tt = v0 * W2[2 * l] + v1 * W2[2 * l + 1];
        tt += __shfl_xor(tt, 1, 8);
        tt += __shfl_xor(tt, 2, 8);
        tt += __shfl_xor(tt, 4, 8);
        if (l == 0) sp[g] = tt * dc;
    }
}

__global__ __launch_bounds__(256) void gather2_kernel(const int* __restrict__ rowptr,
                                                      const int* __restrict__ cnt,
                                                      const int* __restrict__ eidx,
                                                      const float* __restrict__ sp,
                                                      const float* __restrict__ b2,
                                                      float* __restrict__ out, int n) {
    int g = (blockIdx.x * 256 + threadIdx.x) >> 4;
    int lane = threadIdx.x & 15;
    if (g >= n) return;
    int start = rowptr[g];
    int end = start + cnt[g];

    float acc = 0.0f;
    for (int e = start + lane; e < end; e += 16) {
        acc += sp[eidx[e]];
    }
    acc += __shfl_xor(acc, 1, 16);
    acc += __shfl_xor(acc, 2, 16);
    acc += __shfl_xor(acc, 4, 16);
    acc += __shfl_xor(acc, 8, 16);
    if (lane == 0) {
        float v = (acc + sp[g]) * rsqrtf((float)cnt[g] + 1.0f) + b2[0];
        out[g] = 1.0f / (1.0f + __expf(-v));
    }
}

// ===========================================================================
// FALLBACK (proven R4): fixed-cap per-node buckets, fp32 h1p
// ===========================================================================
__global__ void bucket_scatter_kernel(const int* __restrict__ row,
                                      const int* __restrict__ col,
                                      int* __restrict__ cnt,
                                      int* __restrict__ eidx,
                                      int cap, int n_edges) {
    int e = blockIdx.x * blockDim.x + threadIdx.x;
    if (e < n_edges) {
        int c = col[e];
        int p = atomicAdd(&cnt[c], 1);
        if (p < cap) eidx[(size_t)c * cap + p] = row[e];
    }
}

__global__ __launch_bounds__(256) void gemm1f_kernel(const float* __restrict__ x,
                                                     const float* __restrict__ W1,
                                                     const int* __restrict__ cnt,
                                                     float* __restrict__ h1p, int n) {
    __shared__ float sW[F_IN * F_HID];
    int tid = threadIdx.x;
    for (int i = tid; i < F_IN * F_HID; i += 256) sW[i] = W1[i];
    __syncthreads();
    int node = blockIdx.x * 256 + tid;
    if (node >= n) return;
    const float4* xr = (const float4*)(x + (size_t)node * F_IN);
    float acc[F_HID];
#pragma unroll
    for (int j = 0; j < F_HID; j++) acc[j] = 0.0f;
#pragma unroll 4
    for (int k4 = 0; k4 < F_IN / 4; k4++) {
        float4 xv = xr[k4];
        const float* w0 = &sW[(k4 * 4 + 0) * F_HID];
        const float* w1 = &sW[(k4 * 4 + 1) * F_HID];
        const float* w2 = &sW[(k4 * 4 + 2) * F_HID];
        const float* w3 = &sW[(k4 * 4 + 3) * F_HID];
#pragma unroll
        for (int j = 0; j < F_HID; j++) {
            acc[j] += xv.x * w0[j] + xv.y * w1[j] + xv.z * w2[j] + xv.w * w3[j];
        }
    }
    float d = rsqrtf((float)cnt[node] + 1.0f);
    float4* outp = (float4*)(h1p + (size_t)node * F_HID);
    outp[0] = make_float4(acc[0] * d, acc[1] * d, acc[2] * d, acc[3] * d);
    outp[1] = make_float4(acc[4] * d, acc[5] * d, acc[6] * d, acc[7] * d);
    outp[2] = make_float4(acc[8] * d, acc[9] * d, acc[10] * d, acc[11] * d);
    outp[3] = make_float4(acc[12] * d, acc[13] * d, acc[14] * d, acc[15] * d);
}

__global__ __launch_bounds__(256) void fb_gather1_kernel(const int* __restrict__ cnt,
                                                         const int* __restrict__ eidx,
                                                         const float* __restrict__ h1p,
                                                         const float* __restrict__ b1,
                                                         const float* __restrict__ W2,
                                                         float* __restrict__ sp,
                                                         int cap, int n) {
    int g = (blockIdx.x * 256 + threadIdx.x) >> 4;
    int lane = threadIdx.x & 15;
    if (g >= n) return;
    int start = g * cap;
    int end = start + min(cnt[g], cap);
    float acc = 0.0f;
    for (int base = start; base < end; base += 16) {
        int e = base + lane;
        int r = (e < end) ? eidx[e] : 0;
        int m_cnt = min(16, end - base);
        for (int m = 0; m < m_cnt; m++) {
            int rm = __shfl(r, m, 16);
            acc += h1p[(size_t)rm * F_HID + lane];
        }
    }
    float dc = rsqrtf((float)cnt[g] + 1.0f);
    float v = (acc + h1p[(size_t)g * F_HID + lane]) * dc + b1[lane];
    v = fmaxf(v, 0.0f);
    float t = v * W2[lane];
    t += __shfl_xor(t, 1, 16);
    t += __shfl_xor(t, 2, 16);
    t += __shfl_xor(t, 4, 16);
    t += __shfl_xor(t, 8, 16);
    if (lane == 0) sp[g] = t * dc;
}

__global__ __launch_bounds__(256) void fb_gather2_kernel(const int* __restrict__ cnt,
                                                         const int* __restrict__ eidx,
                                                         const float* __restrict__ sp,
                                                         const float* __restrict__ b2,
                                                         float* __restrict__ out,
                                                         int cap, int n) {
    int g = (blockIdx.x * 256 + threadIdx.x) >> 4;
    int lane = threadIdx.x & 15;
    if (g >= n) return;
    int start = g * cap;
    int end = start + min(cnt[g], cap);
    float acc = 0.0f;
    for (int e = start + lane; e < end; e += 16) {
        acc += sp[eidx[e]];
    }
    acc += __shfl_xor(acc, 1, 16);
    acc += __shfl_xor(acc, 2, 16);
    acc += __shfl_xor(acc, 4, 16);
    acc += __shfl_xor(acc, 8, 16);
    if (lane == 0) {
        float v = (acc + sp[g]) * rsqrtf((float)cnt[g] + 1.0f) + b2[0];
        out[g] = 1.0f / (1.0f + __expf(-v));
    }
}

extern "C" void kernel_launch(void* const* d_in, const int* in_sizes, int n_in,
                              void* d_out, int out_size, void* d_ws, size_t ws_size,
                              hipStream_t stream) {
    const float* x  = (const float*)d_in[0];
    const int*   ei = (const int*)d_in[1];  // [2, E] flat: row then col
    const float* W1 = (const float*)d_in[2];
    const float* b1 = (const float*)d_in[3];
    const float* W2 = (const float*)d_in[4];
    const float* b2 = (const float*)d_in[5];
    float* out = (float*)d_out;

    const int n = in_sizes[0] / F_IN;      // 100000
    const int n_edges = in_sizes[1] / 2;   // 3200000
    const int* row = ei;
    const int* col = ei + n_edges;

    const size_t S = ((size_t)n + 511) & ~(size_t)511;
    const size_t words = ws_size / 4;

    const int B = 256;
    const int gridE = (n_edges + B - 1) / B;
    const int gridN = (n + B - 1) / B;

    const int NB = (n + 255) >> 8;
    int meanB = (NB > 0) ? (n_edges / NB) : 0;
    int capB = ((meanB + meanB / 8 + 1024) + 15) & ~15;  // mean + 12% + slack
    // Layout (words): cnt[S] | cursor[NBMAX] | rowptr[S] | sp[S] |
    //                 h1p(half16)[8S] | ping[NB*capB] | pong[NB*capB, fallback]
    size_t need_new = 11 * S + (size_t)NBMAX + 2 * (size_t)NB * (size_t)capB;

    if (n <= 131072 && NB <= NBMAX && capB <= CAPMAX && words >= need_new) {
        int*    cnt    = (int*)d_ws;
        int*    cursor = cnt + S;
        int*    rowptr = cursor + NBMAX;
        float*  sp     = (float*)(rowptr + S);
        __half* h1p    = (__half*)(sp + S);
        int*    ping   = (int*)(sp + S) + 8 * S;
        int*    pong   = ping + (size_t)NB * capB;

        hipMemsetAsync(cursor, 0, NBMAX * sizeof(int), stream);
        int ntiles = (n_edges + PT - 1) / PT;
        int pgrid = min(2048, ntiles);
        partition_kernel<<<pgrid, PB, 0, stream>>>(row, col, cursor, ping,
                                                   capB, NB, n_edges);
        deg_gemm1_kernel<<<NB, PB, 0, stream>>>(cursor, ping, x, W1, cnt,
                                                rowptr, h1p, capB, n);

        // cooperative fused gather1+gather2 (2 blocks/CU * 256 CU = 512 >= NB)
        {
            const int*    a_cursor = cursor;  const int* a_ping = ping;
            const int*    a_cnt = cnt;        const int* a_rowptr = rowptr;
            const __half* a_h1p = h1p;        const float* a_b1 = b1;
            const float*  a_W2 = W2;          float* a_sp = sp;
            const float*  a_b2 = b2;          float* a_out = out;
            int a_capB = capB;                int a_n = n;
            void* args[] = {&a_cursor, &a_ping, &a_cnt, &a_rowptr, &a_h1p,
                            &a_b1, &a_W2, &a_sp, &a_b2, &a_out, &a_capB, &a_n};
            hipError_t cerr = hipLaunchCooperativeKernel(
                (void*)sort_gather12, dim3(NB), dim3(PB), args,
                (size_t)capB * sizeof(int), stream);
            if (cerr != hipSuccess) {
                // fallback: proven split pair (uses pong)
                sort_gather1<<<NB, PB, (size_t)capB * sizeof(int), stream>>>(
                    cursor, ping, cnt, rowptr, h1p, b1, W2, sp, pong, capB, n);
                int gridG2 = (n * 16 + B - 1) / B;
                gather2_kernel<<<gridG2, B, 0, stream>>>(rowptr, cnt, pong, sp,
                                                         b2, out, n);
            }
        }
    } else {
        // FALLBACK (R4): cnt[S] | sp[S] | h1pf[16S] | eidx[n*cap]
        int*   cnt  = (int*)d_ws;
        float* sp   = (float*)(cnt + S);
        float* h1pf = sp + S;
        int*   eidx = (int*)(h1pf + 16 * S);
        size_t tail_words = (words > 18 * S) ? (words - 18 * S) : 0;
        int cap = (int)min((size_t)96, tail_words / (size_t)(n > 0 ? n : 1));
        const int gridG = (n * 16 + B - 1) / B;

        hipMemsetAsync(cnt, 0, (size_t)n * sizeof(int), stream);
        bucket_scatter_kernel<<<gridE, B, 0, stream>>>(row, col, cnt, eidx, cap, n_edges);
        gemm1f_kernel<<<gridN, B, 0, stream>>>(x, W1, cnt, h1pf, n);
        fb_gather1_kernel<<<gridG, B, 0, stream>>>(cnt, eidx, h1pf, b1, W2, sp, cap, n);
        fb_gather2_kernel<<<gridG, B, 0, stream>>>(cnt, eidx, sp, b2, out, cap, n);
    }
}

// Round 9
// 198.521 us; speedup vs baseline: 1.7816x; 1.7816x over previous
//
#include <hip/hip_runtime.h>
#include <hip/hip_fp16.h>
#include <cstdint>

// R21: R20 retry -- fix compile error. __builtin_nontemporal_load rejects
// HIP_vector_type (int4/float4 structs); use Clang ext_vector_type aliases.
// Base = R18 (178.3us best). NT hints on single-use streams (edges in
// partition, x in deg_gemm1) keep ping (re-read 2x) and h1p (gathered
// ~100MB) L2-resident after the harness's 268MB workspace poison-fill.
// Session evidence: R12 197; R13 610 (latency-chain gather); R14 296
// (global-atomic cnt); R15 182.1; R16 189.3; R17 185.8; R18 178.3;
// R19 353.7 (coop grid-sync fusion -- NEVER again); R20 compile-fail.

#define F_IN 128
#define F_HID 16
#define PB 1024           // partition / deg_gemm1 / sort_gather1 block threads
#define PT 8192           // edges per partition tile
#define NBMAX 512         // max buckets (nodes/256), n <= 131072
#define CAPMAX 15104      // max bucket capacity (LDS B[capB] must fit 64KB)

typedef int   vint4   __attribute__((ext_vector_type(4)));
typedef float vfloat4 __attribute__((ext_vector_type(4)));

// ===========================================================================
// Phase 1: counting-sort partition into 256-node dst buckets (R15-exact +
// nontemporal edge loads; edges are never re-read).
// Packed edge word: r | (c&255)<<17  (needs n <= 2^17). int4 edge loads.
// ===========================================================================
__global__ __launch_bounds__(PB) void partition_kernel(
    const int* __restrict__ row, const int* __restrict__ col,
    int* __restrict__ cursor,        // [NBMAX], zeroed
    int* __restrict__ ping,          // [NB * capB]
    int capB, int NB, int n_edges) {
    __shared__ int sh_hist[NBMAX];
    __shared__ int sh_scan[NBMAX];
    __shared__ int sh_cur[NBMAX];
    __shared__ int sh_base[NBMAX];
    __shared__ int sh_wsum[16];
    __shared__ int sh_packed[PT];
    __shared__ unsigned short sh_bkt[PT];

    int t = threadIdx.x;
    int lane = t & 63;
    int wv = t >> 6;
    int ntiles = (n_edges + PT - 1) / PT;
    bool vec_ok = ((n_edges & 3) == 0);   // col = row + n_edges 16B-aligned

    for (int tile = blockIdx.x; tile < ntiles; tile += gridDim.x) {
        int tbase = tile * PT;
        int tcnt = min(PT, n_edges - tbase);

        if (t < NBMAX) sh_hist[t] = 0;
        __syncthreads();

        int e0 = tbase + t * 8;
        int pk[8], bb[8];
        if (vec_ok && e0 + 8 <= n_edges) {
            vint4 a0 = __builtin_nontemporal_load((const vint4*)(row + e0));
            vint4 a1 = __builtin_nontemporal_load((const vint4*)(row + e0 + 4));
            vint4 c0 = __builtin_nontemporal_load((const vint4*)(col + e0));
            vint4 c1 = __builtin_nontemporal_load((const vint4*)(col + e0 + 4));
            int rr[8] = {a0.x, a0.y, a0.z, a0.w, a1.x, a1.y, a1.z, a1.w};
            int cc[8] = {c0.x, c0.y, c0.z, c0.w, c1.x, c1.y, c1.z, c1.w};
#pragma unroll
            for (int k = 0; k < 8; k++) {
                bb[k] = cc[k] >> 8;
                pk[k] = rr[k] | ((cc[k] & 255) << 17);
                atomicAdd(&sh_hist[bb[k]], 1);
            }
        } else {
#pragma unroll
            for (int k = 0; k < 8; k++) {
                int e = e0 + k;
                bb[k] = -1;
                if (e < n_edges) {
                    int r = row[e];
                    int c = col[e];
                    bb[k] = c >> 8;
                    pk[k] = r | ((c & 255) << 17);
                    atomicAdd(&sh_hist[bb[k]], 1);
                }
            }
        }
        __syncthreads();

        // wave-hierarchical inclusive scan of sh_hist[0..511]
        {
            int v = (t < NBMAX) ? sh_hist[t] : 0;
            int incl = v;
#pragma unroll
            for (int off = 1; off < 64; off <<= 1) {
                int u = __shfl_up(incl, off, 64);
                if (lane >= off) incl += u;
            }
            if (lane == 63) sh_wsum[wv] = incl;
            __syncthreads();
            if (t < 16) {
                int s = sh_wsum[t];
#pragma unroll
                for (int off = 1; off < 16; off <<= 1) {
                    int u = __shfl_up(s, off, 16);
                    if (t >= off) s += u;
                }
                sh_wsum[t] = s;
            }
            __syncthreads();
            int wexcl = (wv > 0) ? sh_wsum[wv - 1] : 0;
            if (t < NBMAX) sh_scan[t] = incl + wexcl;
        }
        __syncthreads();

        if (t < NBMAX) {
            int h = sh_hist[t];
            sh_cur[t] = sh_scan[t] - h;
            sh_base[t] = (h > 0 && t < NB) ? atomicAdd(&cursor[t], h) : 0;
        }
        __syncthreads();

        // LDS reorder scatter
#pragma unroll
        for (int k = 0; k < 8; k++) {
            if (bb[k] >= 0) {
                int p = atomicAdd(&sh_cur[bb[k]], 1);
                sh_packed[p] = pk[k];
                sh_bkt[p] = (unsigned short)bb[k];
            }
        }
        __syncthreads();

        // write runs out bucket-contiguously
#pragma unroll
        for (int k = 0; k < 8; k++) {
            int p = t + k * PB;
            if (p < tcnt) {
                int b = sh_bkt[p];
                int off = p - (sh_scan[b] - sh_hist[b]);
                int gp = sh_base[b] + off;
                if (gp < capB) ping[(size_t)b * capB + gp] = sh_packed[p];
            }
        }
        __syncthreads();
    }
}

// ===========================================================================
// Phase 2 (merged, 1024 thr): per-bucket degree histogram (phase A, full
// block) + gemm1 (phase B, j-split: 4 threads/node, 4 outputs each).
// Block b's node range [256b, 256b+256) == bucket b's range.
// x loads nontemporal (single-use stream) to keep ping/h1p L2-resident.
// h1p = fp16( (x @ W1) * dinv[node] ), cnt/rowptr written for later kernels.
// ===========================================================================
__global__ __launch_bounds__(PB) void deg_gemm1_kernel(
    const int* __restrict__ cursor, const int* __restrict__ ping,
    const float* __restrict__ x, const float* __restrict__ W1,
    int* __restrict__ cnt, int* __restrict__ rowptr,
    __half* __restrict__ h1p, int capB, int n) {
    __shared__ float sW[F_IN * F_HID];
    __shared__ int hist[256];
    __shared__ int wsum[4];

    int b = blockIdx.x, t = threadIdx.x;
    int lane = t & 63;
    int wv = t >> 6;

    // weight staging (barrier below covers it)
    for (int i = t; i < F_IN * F_HID; i += PB) sW[i] = W1[i];
    if (t < 256) hist[t] = 0;
    __syncthreads();

    // phase A: histogram bucket edges by sub-index (node within bucket)
    int cb = min(cursor[b], capB);
    const int* src = ping + (size_t)b * capB;
    for (int i = t; i < cb; i += PB) {
        atomicAdd(&hist[(src[i] >> 17) & 255], 1);
    }
    __syncthreads();

    // inclusive scan of hist[0..255] (first 4 waves carry data)
    {
        int h = (t < 256) ? hist[t] : 0;
        int incl = h;
#pragma unroll
        for (int off = 1; off < 64; off <<= 1) {
            int u = __shfl_up(incl, off, 64);
            if (lane >= off) incl += u;
        }
        if (t < 256 && lane == 63) wsum[wv] = incl;
        __syncthreads();
        if (t < 4) {
            int s = wsum[t];
#pragma unroll
            for (int off = 1; off < 4; off <<= 1) {
                int u = __shfl_up(s, off, 4);
                if (t >= off) s += u;
            }
            wsum[t] = s;
        }
        __syncthreads();
        if (t < 256) {
            int g = b * 256 + t;
            if (g < n) {
                int wexcl = (wv > 0) ? wsum[wv - 1] : 0;
                cnt[g] = h;
                rowptr[g] = b * capB + (incl + wexcl - h);
            }
        }
    }
    // hist[] untouched by scan -> safe to read below without extra barrier

    // phase B: gemm1, 4 threads per node, 4 output features each
    int sub = t >> 2;
    int node = b * 256 + sub;
    if (node >= n) return;
    int jq = (t & 3) * 4;

    const vfloat4* xr = (const vfloat4*)(x + (size_t)node * F_IN);
    float a0 = 0.0f, a1 = 0.0f, a2 = 0.0f, a3 = 0.0f;

#pragma unroll 4
    for (int k4 = 0; k4 < F_IN / 4; k4++) {
        vfloat4 xv = __builtin_nontemporal_load(xr + k4);
        const float* w0 = &sW[(k4 * 4 + 0) * F_HID + jq];
        const float* w1 = &sW[(k4 * 4 + 1) * F_HID + jq];
        const float* w2 = &sW[(k4 * 4 + 2) * F_HID + jq];
        const float* w3 = &sW[(k4 * 4 + 3) * F_HID + jq];
        a0 += xv.x * w0[0] + xv.y * w1[0] + xv.z * w2[0] + xv.w * w3[0];
        a1 += xv.x * w0[1] + xv.y * w1[1] + xv.z * w2[1] + xv.w * w3[1];
        a2 += xv.x * w0[2] + xv.y * w1[2] + xv.z * w2[2] + xv.w * w3[2];
        a3 += xv.x * w0[3] + xv.y * w1[3] + xv.z * w2[3] + xv.w * w3[3];
    }

    float d = rsqrtf((float)hist[sub] + 1.0f);
    __half2 hv[2];
    hv[0] = __floats2half2_rn(a0 * d, a1 * d);
    hv[1] = __floats2half2_rn(a2 * d, a3 * d);
    *(float2*)(h1p + (size_t)node * F_HID + jq) = *(float2*)&hv[0];
}

// ===========================================================================
// Phase 3: fused per-bucket counting sort (LDS) + layer-1 windowed gather.
// hist/scan come precomputed from deg_gemm1 (cnt/rowptr):
//  pass A: scatter ping -> LDS B[] sorted    pass B: coalesced B -> pong
//  pass C: R12-style windowed gather, 8 lanes/node, edges from LDS
// ===========================================================================
__global__ __launch_bounds__(PB) void sort_gather1(
    const int* __restrict__ cursor, const int* __restrict__ ping,
    const int* __restrict__ cnt, const int* __restrict__ rowptr,
    const __half* __restrict__ h1p, const float* __restrict__ b1,
    const float* __restrict__ W2, float* __restrict__ sp,
    int* __restrict__ pong, int capB, int n) {
    extern __shared__ int B[];        // capB ints (sorted edge srcs)
    __shared__ int s_excl[256];
    __shared__ int s_h[256];
    __shared__ int cur[256];

    int b = blockIdx.x, t = threadIdx.x;

    if (t < 256) {
        int g = b * 256 + t;
        int h = (g < n) ? cnt[g] : 0;
        int excl = (g < n) ? (rowptr[g] - b * capB) : 0;
        s_h[t] = h;
        s_excl[t] = excl;
        cur[t] = excl;
    }
    __syncthreads();

    int cb = min(cursor[b], capB);
    const int* src = ping + (size_t)b * capB;

    // counting scatter into LDS (ping is L2-hot, NT hints upstream)
    for (int i = t; i < cb; i += PB) {
        int v = src[i];
        int p = atomicAdd(&cur[(v >> 17) & 255], 1);
        B[p] = v & 131071;
    }
    __syncthreads();

    // coalesced pong write-out (for gather2); drains under the gather below
    for (int i = t; i < cb; i += PB) {
        pong[(size_t)b * capB + i] = B[i];
    }

    // windowed gather: 8 lanes per node, 8 independent h1p loads per window
    int l = t & 7;
    for (int j = t >> 3; j < 256; j += (PB >> 3)) {
        int g = b * 256 + j;
        if (g >= n) continue;
        int h = s_h[j];
        int base = s_excl[j];
        int end = base + h;

        float ax = 0.0f, ay = 0.0f;
        for (; base + 8 <= end; base += 8) {
#pragma unroll
            for (int m = 0; m < 8; m++) {
                int rm = B[base + m];
                float2 f = __half22float2(*(const __half2*)(h1p + (size_t)rm * F_HID + 2 * l));
                ax += f.x; ay += f.y;
            }
        }
        for (int m = 0; m < end - base; m++) {
            int rm = B[base + m];
            float2 f = __half22float2(*(const __half2*)(h1p + (size_t)rm * F_HID + 2 * l));
            ax += f.x; ay += f.y;
        }

        float dc = rsqrtf((float)h + 1.0f);
        float2 fs = __half22float2(*(const __half2*)(h1p + (size_t)g * F_HID + 2 * l));
        float v0 = (ax + fs.x) * dc + b1[2 * l];
        float v1 = (ay + fs.y) * dc + b1[2 * l + 1];
        v0 = fmaxf(v0, 0.0f);
        v1 = fmaxf(v1, 0.0f);
        float tt = v0 * W2[2 * l] + v1 * W2[2 * l + 1];  // fused [16,1] GEMM
        tt += __shfl_xor(tt, 1, 8);
        tt += __shfl_xor(tt, 2, 8);
        tt += __shfl_xor(tt, 4, 8);
        if (l == 0) sp[g] = tt * dc;   // pre-scale by src norm for layer 2
    }
}

// ===========================================================================
// Phase 4: layer-2 gather + sigmoid (16 lanes per node) — unchanged R12
// ===========================================================================
__global__ __launch_bounds__(256) void gather2_kernel(const int* __restrict__ rowptr,
                                                      const int* __restrict__ cnt,
                                                      const int* __restrict__ eidx,
                                                      const float* __restrict__ sp,
                                                      const float* __restrict__ b2,
                                                      float* __restrict__ out, int n) {
    int g = (blockIdx.x * 256 + threadIdx.x) >> 4;
    int lane = threadIdx.x & 15;
    if (g >= n) return;
    int start = rowptr[g];
    int end = start + cnt[g];

    float acc = 0.0f;
    for (int e = start + lane; e < end; e += 16) {
        acc += sp[eidx[e]];
    }
    acc += __shfl_xor(acc, 1, 16);
    acc += __shfl_xor(acc, 2, 16);
    acc += __shfl_xor(acc, 4, 16);
    acc += __shfl_xor(acc, 8, 16);
    if (lane == 0) {
        float v = (acc + sp[g]) * rsqrtf((float)cnt[g] + 1.0f) + b2[0];
        out[g] = 1.0f / (1.0f + __expf(-v));
    }
}

// ===========================================================================
// FALLBACK (proven R4): fixed-cap per-node buckets, fp32 h1p
// ===========================================================================
__global__ void bucket_scatter_kernel(const int* __restrict__ row,
                                      const int* __restrict__ col,
                                      int* __restrict__ cnt,
                                      int* __restrict__ eidx,
                                      int cap, int n_edges) {
    int e = blockIdx.x * blockDim.x + threadIdx.x;
    if (e < n_edges) {
        int c = col[e];
        int p = atomicAdd(&cnt[c], 1);
        if (p < cap) eidx[(size_t)c * cap + p] = row[e];
    }
}

__global__ __launch_bounds__(256) void gemm1f_kernel(const float* __restrict__ x,
                                                     const float* __restrict__ W1,
                                                     const int* __restrict__ cnt,
                                                     float* __restrict__ h1p, int n) {
    __shared__ float sW[F_IN * F_HID];
    int tid = threadIdx.x;
    for (int i = tid; i < F_IN * F_HID; i += 256) sW[i] = W1[i];
    __syncthreads();
    int node = blockIdx.x * 256 + tid;
    if (node >= n) return;
    const float4* xr = (const float4*)(x + (size_t)node * F_IN);
    float acc[F_HID];
#pragma unroll
    for (int j = 0; j < F_HID; j++) acc[j] = 0.0f;
#pragma unroll 4
    for (int k4 = 0; k4 < F_IN / 4; k4++) {
        float4 xv = xr[k4];
        const float* w0 = &sW[(k4 * 4 + 0) * F_HID];
        const float* w1 = &sW[(k4 * 4 + 1) * F_HID];
        const float* w2 = &sW[(k4 * 4 + 2) * F_HID];
        const float* w3 = &sW[(k4 * 4 + 3) * F_HID];
#pragma unroll
        for (int j = 0; j < F_HID; j++) {
            acc[j] += xv.x * w0[j] + xv.y * w1[j] + xv.z * w2[j] + xv.w * w3[j];
        }
    }
    float d = rsqrtf((float)cnt[node] + 1.0f);
    float4* outp = (float4*)(h1p + (size_t)node * F_HID);
    outp[0] = make_float4(acc[0] * d, acc[1] * d, acc[2] * d, acc[3] * d);
    outp[1] = make_float4(acc[4] * d, acc[5] * d, acc[6] * d, acc[7] * d);
    outp[2] = make_float4(acc[8] * d, acc[9] * d, acc[10] * d, acc[11] * d);
    outp[3] = make_float4(acc[12] * d, acc[13] * d, acc[14] * d, acc[15] * d);
}

__global__ __launch_bounds__(256) void fb_gather1_kernel(const int* __restrict__ cnt,
                                                         const int* __restrict__ eidx,
                                                         const float* __restrict__ h1p,
                                                         const float* __restrict__ b1,
                                                         const float* __restrict__ W2,
                                                         float* __restrict__ sp,
                                                         int cap, int n) {
    int g = (blockIdx.x * 256 + threadIdx.x) >> 4;
    int lane = threadIdx.x & 15;
    if (g >= n) return;
    int start = g * cap;
    int end = start + min(cnt[g], cap);
    float acc = 0.0f;
    for (int base = start; base < end; base += 16) {
        int e = base + lane;
        int r = (e < end) ? eidx[e] : 0;
        int m_cnt = min(16, end - base);
        for (int m = 0; m < m_cnt; m++) {
            int rm = __shfl(r, m, 16);
            acc += h1p[(size_t)rm * F_HID + lane];
        }
    }
    float dc = rsqrtf((float)cnt[g] + 1.0f);
    float v = (acc + h1p[(size_t)g * F_HID + lane]) * dc + b1[lane];
    v = fmaxf(v, 0.0f);
    float t = v * W2[lane];
    t += __shfl_xor(t, 1, 16);
    t += __shfl_xor(t, 2, 16);
    t += __shfl_xor(t, 4, 16);
    t += __shfl_xor(t, 8, 16);
    if (lane == 0) sp[g] = t * dc;
}

__global__ __launch_bounds__(256) void fb_gather2_kernel(const int* __restrict__ cnt,
                                                         const int* __restrict__ eidx,
                                                         const float* __restrict__ sp,
                                                         const float* __restrict__ b2,
                                                         float* __restrict__ out,
                                                         int cap, int n) {
    int g = (blockIdx.x * 256 + threadIdx.x) >> 4;
    int lane = threadIdx.x & 15;
    if (g >= n) return;
    int start = g * cap;
    int end = start + min(cnt[g], cap);
    float acc = 0.0f;
    for (int e = start + lane; e < end; e += 16) {
        acc += sp[eidx[e]];
    }
    acc += __shfl_xor(acc, 1, 16);
    acc += __shfl_xor(acc, 2, 16);
    acc += __shfl_xor(acc, 4, 16);
    acc += __shfl_xor(acc, 8, 16);
    if (lane == 0) {
        float v = (acc + sp[g]) * rsqrtf((float)cnt[g] + 1.0f) + b2[0];
        out[g] = 1.0f / (1.0f + __expf(-v));
    }
}

extern "C" void kernel_launch(void* const* d_in, const int* in_sizes, int n_in,
                              void* d_out, int out_size, void* d_ws, size_t ws_size,
                              hipStream_t stream) {
    const float* x  = (const float*)d_in[0];
    const int*   ei = (const int*)d_in[1];  // [2, E] flat: row then col
    const float* W1 = (const float*)d_in[2];
    const float* b1 = (const float*)d_in[3];
    const float* W2 = (const float*)d_in[4];
    const float* b2 = (const float*)d_in[5];
    float* out = (float*)d_out;

    const int n = in_sizes[0] / F_IN;      // 100000
    const int n_edges = in_sizes[1] / 2;   // 3200000
    const int* row = ei;
    const int* col = ei + n_edges;

    const size_t S = ((size_t)n + 511) & ~(size_t)511;
    const size_t words = ws_size / 4;

    const int B = 256;
    const int gridE = (n_edges + B - 1) / B;
    const int gridN = (n + B - 1) / B;

    const int NB = (n + 255) >> 8;
    int meanB = (NB > 0) ? (n_edges / NB) : 0;
    int capB = ((meanB + meanB / 8 + 1024) + 15) & ~15;  // mean + 12% + slack
    // Layout (words): cnt[S] | cursor[NBMAX] | rowptr[S] | sp[S] |
    //                 h1p(half16)[8S] | ping[NB*capB] | pong[NB*capB]
    size_t need_new = 11 * S + (size_t)NBMAX + 2 * (size_t)NB * (size_t)capB;

    if (n <= 131072 && NB <= NBMAX && capB <= CAPMAX && words >= need_new) {
        int*    cnt    = (int*)d_ws;
        int*    cursor = cnt + S;
        int*    rowptr = cursor + NBMAX;
        float*  sp     = (float*)(rowptr + S);
        __half* h1p    = (__half*)(sp + S);
        int*    ping   = (int*)(sp + S) + 8 * S;
        int*    pong   = ping + (size_t)NB * capB;

        (void)hipMemsetAsync(cursor, 0, NBMAX * sizeof(int), stream);
        int ntiles = (n_edges + PT - 1) / PT;
        int pgrid = min(2048, ntiles);
        partition_kernel<<<pgrid, PB, 0, stream>>>(row, col, cursor, ping,
                                                   capB, NB, n_edges);
        deg_gemm1_kernel<<<NB, PB, 0, stream>>>(cursor, ping, x, W1, cnt,
                                                rowptr, h1p, capB, n);
        sort_gather1<<<NB, PB, (size_t)capB * sizeof(int), stream>>>(
            cursor, ping, cnt, rowptr, h1p, b1, W2, sp, pong, capB, n);
        int gridG2 = (n * 16 + B - 1) / B;  // 16 lanes per node
        gather2_kernel<<<gridG2, B, 0, stream>>>(rowptr, cnt, pong, sp, b2, out, n);
    } else {
        // FALLBACK (R4): cnt[S] | sp[S] | h1pf[16S] | eidx[n*cap]
        int*   cnt  = (int*)d_ws;
        float* sp   = (float*)(cnt + S);
        float* h1pf = sp + S;
        int*   eidx = (int*)(h1pf + 16 * S);
        size_t tail_words = (words > 18 * S) ? (words - 18 * S) : 0;
        int cap = (int)min((size_t)96, tail_words / (size_t)(n > 0 ? n : 1));
        const int gridG = (n * 16 + B - 1) / B;

        (void)hipMemsetAsync(cnt, 0, (size_t)n * sizeof(int), stream);
        bucket_scatter_kernel<<<gridE, B, 0, stream>>>(row, col, cnt, eidx, cap, n_edges);
        gemm1f_kernel<<<gridN, B, 0, stream>>>(x, W1, cnt, h1pf, n);
        fb_gather1_kernel<<<gridG, B, 0, stream>>>(cnt, eidx, h1pf, b1, W2, sp, cap, n);
        fb_gather2_kernel<<<gridG, B, 0, stream>>>(cnt, eidx, sp, b2, out, cap, n);
    }
}

// Round 10
// 179.713 us; speedup vs baseline: 1.9680x; 1.1047x over previous
//
#include <hip/hip_runtime.h>
#include <hip/hip_fp16.h>
#include <cstdint>

// R22: revert ALL nontemporal hints (R21 = 198.5us regression; NT bypasses
// L1 so the j-split gemm's 4-lane-shared x float4 loads stopped merging ->
// 4x L2 traffic, deg_gemm1 44us). Back to R18 memory ops exactly.
// One isolated change: partition tile PPB=896/PT=7168 -> 447 tiles over
// 512 residency slots; worst CU = 2x7168 = 14336 edges (-12.5% vs 2x8192)
// with the SAME per-CU fixed cost count (R16's PT=4096 added a 3rd fixed
// cost per CU -- that was the mistake).
// Session evidence: R12 197; R13 610 (latency-chain gather); R14 296
// (global-atomic cnt); R15 182.1; R16 189.3; R17 185.8; R18 178.3 BEST;
// R19 353.7 (coop grid-sync -- never); R20 compile-fail; R21 198.5 (NT).

#define F_IN 128
#define F_HID 16
#define PB 1024           // deg_gemm1 / sort_gather1 block threads
#define PPB 896           // partition block threads (14 waves)
#define PT 7168           // edges per partition tile = PPB * 8
#define NBMAX 512         // max buckets (nodes/256), n <= 131072
#define CAPMAX 15104      // max bucket capacity (LDS B[capB] must fit 64KB)

// ===========================================================================
// Phase 1: counting-sort partition into 256-node dst buckets.
// Packed edge word: r | (c&255)<<17  (needs n <= 2^17). int4 edge loads.
// ===========================================================================
__global__ __launch_bounds__(PPB) void partition_kernel(
    const int* __restrict__ row, const int* __restrict__ col,
    int* __restrict__ cursor,        // [NBMAX], zeroed
    int* __restrict__ ping,          // [NB * capB]
    int capB, int NB, int n_edges) {
    __shared__ int sh_hist[NBMAX];
    __shared__ int sh_scan[NBMAX];
    __shared__ int sh_cur[NBMAX];
    __shared__ int sh_base[NBMAX];
    __shared__ int sh_wsum[16];
    __shared__ int sh_packed[PT];
    __shared__ unsigned short sh_bkt[PT];

    int t = threadIdx.x;
    int lane = t & 63;
    int wv = t >> 6;
    int ntiles = (n_edges + PT - 1) / PT;
    bool vec_ok = ((n_edges & 3) == 0);   // col = row + n_edges 16B-aligned

    for (int tile = blockIdx.x; tile < ntiles; tile += gridDim.x) {
        int tbase = tile * PT;
        int tcnt = min(PT, n_edges - tbase);

        if (t < NBMAX) sh_hist[t] = 0;
        __syncthreads();

        int e0 = tbase + t * 8;
        int pk[8], bb[8];
        if (vec_ok && e0 + 8 <= n_edges) {
            int4 a0 = *(const int4*)(row + e0);
            int4 a1 = *(const int4*)(row + e0 + 4);
            int4 c0 = *(const int4*)(col + e0);
            int4 c1 = *(const int4*)(col + e0 + 4);
            int rr[8] = {a0.x, a0.y, a0.z, a0.w, a1.x, a1.y, a1.z, a1.w};
            int cc[8] = {c0.x, c0.y, c0.z, c0.w, c1.x, c1.y, c1.z, c1.w};
#pragma unroll
            for (int k = 0; k < 8; k++) {
                bb[k] = cc[k] >> 8;
                pk[k] = rr[k] | ((cc[k] & 255) << 17);
                atomicAdd(&sh_hist[bb[k]], 1);
            }
        } else {
#pragma unroll
            for (int k = 0; k < 8; k++) {
                int e = e0 + k;
                bb[k] = -1;
                if (e < n_edges) {
                    int r = row[e];
                    int c = col[e];
                    bb[k] = c >> 8;
                    pk[k] = r | ((c & 255) << 17);
                    atomicAdd(&sh_hist[bb[k]], 1);
                }
            }
        }
        __syncthreads();

        // wave-hierarchical inclusive scan of sh_hist[0..511]
        // (14 waves; only waves 0-7 consume sh_scan, wsum[0..13] all written)
        {
            int v = (t < NBMAX) ? sh_hist[t] : 0;
            int incl = v;
#pragma unroll
            for (int off = 1; off < 64; off <<= 1) {
                int u = __shfl_up(incl, off, 64);
                if (lane >= off) incl += u;
            }
            if (lane == 63) sh_wsum[wv] = incl;
            __syncthreads();
            if (t < 16) {
                int s = (t < (PPB >> 6)) ? sh_wsum[t] : 0;
#pragma unroll
                for (int off = 1; off < 16; off <<= 1) {
                    int u = __shfl_up(s, off, 16);
                    if (t >= off) s += u;
                }
                sh_wsum[t] = s;
            }
            __syncthreads();
            int wexcl = (wv > 0) ? sh_wsum[wv - 1] : 0;
            if (t < NBMAX) sh_scan[t] = incl + wexcl;
        }
        __syncthreads();

        if (t < NBMAX) {
            int h = sh_hist[t];
            sh_cur[t] = sh_scan[t] - h;
            sh_base[t] = (h > 0 && t < NB) ? atomicAdd(&cursor[t], h) : 0;
        }
        __syncthreads();

        // LDS reorder scatter
#pragma unroll
        for (int k = 0; k < 8; k++) {
            if (bb[k] >= 0) {
                int p = atomicAdd(&sh_cur[bb[k]], 1);
                sh_packed[p] = pk[k];
                sh_bkt[p] = (unsigned short)bb[k];
            }
        }
        __syncthreads();

        // write runs out bucket-contiguously
#pragma unroll
        for (int k = 0; k < 8; k++) {
            int p = t + k * PPB;
            if (p < tcnt) {
                int b = sh_bkt[p];
                int off = p - (sh_scan[b] - sh_hist[b]);
                int gp = sh_base[b] + off;
                if (gp < capB) ping[(size_t)b * capB + gp] = sh_packed[p];
            }
        }
        __syncthreads();
    }
}

// ===========================================================================
// Phase 2 (merged, 1024 thr): per-bucket degree histogram (phase A, full
// block) + gemm1 (phase B, j-split: 4 threads/node, 4 outputs each).
// Block b's node range [256b, 256b+256) == bucket b's range.
// h1p = fp16( (x @ W1) * dinv[node] ), cnt/rowptr written for later kernels.
// ===========================================================================
__global__ __launch_bounds__(PB) void deg_gemm1_kernel(
    const int* __restrict__ cursor, const int* __restrict__ ping,
    const float* __restrict__ x, const float* __restrict__ W1,
    int* __restrict__ cnt, int* __restrict__ rowptr,
    __half* __restrict__ h1p, int capB, int n) {
    __shared__ float sW[F_IN * F_HID];
    __shared__ int hist[256];
    __shared__ int wsum[4];

    int b = blockIdx.x, t = threadIdx.x;
    int lane = t & 63;
    int wv = t >> 6;

    // weight staging (barrier below covers it)
    for (int i = t; i < F_IN * F_HID; i += PB) sW[i] = W1[i];
    if (t < 256) hist[t] = 0;
    __syncthreads();

    // phase A: histogram bucket edges by sub-index (node within bucket)
    int cb = min(cursor[b], capB);
    const int* src = ping + (size_t)b * capB;
    for (int i = t; i < cb; i += PB) {
        atomicAdd(&hist[(src[i] >> 17) & 255], 1);
    }
    __syncthreads();

    // inclusive scan of hist[0..255] (first 4 waves carry data)
    {
        int h = (t < 256) ? hist[t] : 0;
        int incl = h;
#pragma unroll
        for (int off = 1; off < 64; off <<= 1) {
            int u = __shfl_up(incl, off, 64);
            if (lane >= off) incl += u;
        }
        if (t < 256 && lane == 63) wsum[wv] = incl;
        __syncthreads();
        if (t < 4) {
            int s = wsum[t];
#pragma unroll
            for (int off = 1; off < 4; off <<= 1) {
                int u = __shfl_up(s, off, 4);
                if (t >= off) s += u;
            }
            wsum[t] = s;
        }
        __syncthreads();
        if (t < 256) {
            int g = b * 256 + t;
            if (g < n) {
                int wexcl = (wv > 0) ? wsum[wv - 1] : 0;
                cnt[g] = h;
                rowptr[g] = b * capB + (incl + wexcl - h);
            }
        }
    }
    // hist[] untouched by scan -> safe to read below without extra barrier

    // phase B: gemm1, 4 threads per node, 4 output features each
    int sub = t >> 2;
    int node = b * 256 + sub;
    if (node >= n) return;
    int jq = (t & 3) * 4;

    const float4* xr = (const float4*)(x + (size_t)node * F_IN);
    float a0 = 0.0f, a1 = 0.0f, a2 = 0.0f, a3 = 0.0f;

#pragma unroll 4
    for (int k4 = 0; k4 < F_IN / 4; k4++) {
        float4 xv = xr[k4];
        const float* w0 = &sW[(k4 * 4 + 0) * F_HID + jq];
        const float* w1 = &sW[(k4 * 4 + 1) * F_HID + jq];
        const float* w2 = &sW[(k4 * 4 + 2) * F_HID + jq];
        const float* w3 = &sW[(k4 * 4 + 3) * F_HID + jq];
        a0 += xv.x * w0[0] + xv.y * w1[0] + xv.z * w2[0] + xv.w * w3[0];
        a1 += xv.x * w0[1] + xv.y * w1[1] + xv.z * w2[1] + xv.w * w3[1];
        a2 += xv.x * w0[2] + xv.y * w1[2] + xv.z * w2[2] + xv.w * w3[2];
        a3 += xv.x * w0[3] + xv.y * w1[3] + xv.z * w2[3] + xv.w * w3[3];
    }

    float d = rsqrtf((float)hist[sub] + 1.0f);
    __half2 hv[2];
    hv[0] = __floats2half2_rn(a0 * d, a1 * d);
    hv[1] = __floats2half2_rn(a2 * d, a3 * d);
    *(float2*)(h1p + (size_t)node * F_HID + jq) = *(float2*)&hv[0];
}

// ===========================================================================
// Phase 3: fused per-bucket counting sort (LDS) + layer-1 windowed gather.
// hist/scan come precomputed from deg_gemm1 (cnt/rowptr):
//  pass A: scatter ping -> LDS B[] sorted    pass B: coalesced B -> pong
//  pass C: R12-style windowed gather, 8 lanes/node, edges from LDS
// ===========================================================================
__global__ __launch_bounds__(PB) void sort_gather1(
    const int* __restrict__ cursor, const int* __restrict__ ping,
    const int* __restrict__ cnt, const int* __restrict__ rowptr,
    const __half* __restrict__ h1p, const float* __restrict__ b1,
    const float* __restrict__ W2, float* __restrict__ sp,
    int* __restrict__ pong, int capB, int n) {
    extern __shared__ int B[];        // capB ints (sorted edge srcs)
    __shared__ int s_excl[256];
    __shared__ int s_h[256];
    __shared__ int cur[256];

    int b = blockIdx.x, t = threadIdx.x;

    if (t < 256) {
        int g = b * 256 + t;
        int h = (g < n) ? cnt[g] : 0;
        int excl = (g < n) ? (rowptr[g] - b * capB) : 0;
        s_h[t] = h;
        s_excl[t] = excl;
        cur[t] = excl;
    }
    __syncthreads();

    int cb = min(cursor[b], capB);
    const int* src = ping + (size_t)b * capB;

    // counting scatter into LDS (ping is L2/L3-hot)
    for (int i = t; i < cb; i += PB) {
        int v = src[i];
        int p = atomicAdd(&cur[(v >> 17) & 255], 1);
        B[p] = v & 131071;
    }
    __syncthreads();

    // coalesced pong write-out (for gather2); drains under the gather below
    for (int i = t; i < cb; i += PB) {
        pong[(size_t)b * capB + i] = B[i];
    }

    // windowed gather: 8 lanes per node, 8 independent h1p loads per window
    int l = t & 7;
    for (int j = t >> 3; j < 256; j += (PB >> 3)) {
        int g = b * 256 + j;
        if (g >= n) continue;
        int h = s_h[j];
        int base = s_excl[j];
        int end = base + h;

        float ax = 0.0f, ay = 0.0f;
        for (; base + 8 <= end; base += 8) {
#pragma unroll
            for (int m = 0; m < 8; m++) {
                int rm = B[base + m];
                float2 f = __half22float2(*(const __half2*)(h1p + (size_t)rm * F_HID + 2 * l));
                ax += f.x; ay += f.y;
            }
        }
        for (int m = 0; m < end - base; m++) {
            int rm = B[base + m];
            float2 f = __half22float2(*(const __half2*)(h1p + (size_t)rm * F_HID + 2 * l));
            ax += f.x; ay += f.y;
        }

        float dc = rsqrtf((float)h + 1.0f);
        float2 fs = __half22float2(*(const __half2*)(h1p + (size_t)g * F_HID + 2 * l));
        float v0 = (ax + fs.x) * dc + b1[2 * l];
        float v1 = (ay + fs.y) * dc + b1[2 * l + 1];
        v0 = fmaxf(v0, 0.0f);
        v1 = fmaxf(v1, 0.0f);
        float tt = v0 * W2[2 * l] + v1 * W2[2 * l + 1];  // fused [16,1] GEMM
        tt += __shfl_xor(tt, 1, 8);
        tt += __shfl_xor(tt, 2, 8);
        tt += __shfl_xor(tt, 4, 8);
        if (l == 0) sp[g] = tt * dc;   // pre-scale by src norm for layer 2
    }
}

// ===========================================================================
// Phase 4: layer-2 gather + sigmoid (16 lanes per node) — unchanged R12
// ===========================================================================
__global__ __launch_bounds__(256) void gather2_kernel(const int* __restrict__ rowptr,
                                                      const int* __restrict__ cnt,
                                                      const int* __restrict__ eidx,
                                                      const float* __restrict__ sp,
                                                      const float* __restrict__ b2,
                                                      float* __restrict__ out, int n) {
    int g = (blockIdx.x * 256 + threadIdx.x) >> 4;
    int lane = threadIdx.x & 15;
    if (g >= n) return;
    int start = rowptr[g];
    int end = start + cnt[g];

    float acc = 0.0f;
    for (int e = start + lane; e < end; e += 16) {
        acc += sp[eidx[e]];
    }
    acc += __shfl_xor(acc, 1, 16);
    acc += __shfl_xor(acc, 2, 16);
    acc += __shfl_xor(acc, 4, 16);
    acc += __shfl_xor(acc, 8, 16);
    if (lane == 0) {
        float v = (acc + sp[g]) * rsqrtf((float)cnt[g] + 1.0f) + b2[0];
        out[g] = 1.0f / (1.0f + __expf(-v));
    }
}

// ===========================================================================
// FALLBACK (proven R4): fixed-cap per-node buckets, fp32 h1p
// ===========================================================================
__global__ void bucket_scatter_kernel(const int* __restrict__ row,
                                      const int* __restrict__ col,
                                      int* __restrict__ cnt,
                                      int* __restrict__ eidx,
                                      int cap, int n_edges) {
    int e = blockIdx.x * blockDim.x + threadIdx.x;
    if (e < n_edges) {
        int c = col[e];
        int p = atomicAdd(&cnt[c], 1);
        if (p < cap) eidx[(size_t)c * cap + p] = row[e];
    }
}

__global__ __launch_bounds__(256) void gemm1f_kernel(const float* __restrict__ x,
                                                     const float* __restrict__ W1,
                                                     const int* __restrict__ cnt,
                                                     float* __restrict__ h1p, int n) {
    __shared__ float sW[F_IN * F_HID];
    int tid = threadIdx.x;
    for (int i = tid; i < F_IN * F_HID; i += 256) sW[i] = W1[i];
    __syncthreads();
    int node = blockIdx.x * 256 + tid;
    if (node >= n) return;
    const float4* xr = (const float4*)(x + (size_t)node * F_IN);
    float acc[F_HID];
#pragma unroll
    for (int j = 0; j < F_HID; j++) acc[j] = 0.0f;
#pragma unroll 4
    for (int k4 = 0; k4 < F_IN / 4; k4++) {
        float4 xv = xr[k4];
        const float* w0 = &sW[(k4 * 4 + 0) * F_HID];
        const float* w1 = &sW[(k4 * 4 + 1) * F_HID];
        const float* w2 = &sW[(k4 * 4 + 2) * F_HID];
        const float* w3 = &sW[(k4 * 4 + 3) * F_HID];
#pragma unroll
        for (int j = 0; j < F_HID; j++) {
            acc[j] += xv.x * w0[j] + xv.y * w1[j] + xv.z * w2[j] + xv.w * w3[j];
        }
    }
    float d = rsqrtf((float)cnt[node] + 1.0f);
    float4* outp = (float4*)(h1p + (size_t)node * F_HID);
    outp[0] = make_float4(acc[0] * d, acc[1] * d, acc[2] * d, acc[3] * d);
    outp[1] = make_float4(acc[4] * d, acc[5] * d, acc[6] * d, acc[7] * d);
    outp[2] = make_float4(acc[8] * d, acc[9] * d, acc[10] * d, acc[11] * d);
    outp[3] = make_float4(acc[12] * d, acc[13] * d, acc[14] * d, acc[15] * d);
}

__global__ __launch_bounds__(256) void fb_gather1_kernel(const int* __restrict__ cnt,
                                                         const int* __restrict__ eidx,
                                                         const float* __restrict__ h1p,
                                                         const float* __restrict__ b1,
                                                         const float* __restrict__ W2,
                                                         float* __restrict__ sp,
                                                         int cap, int n) {
    int g = (blockIdx.x * 256 + threadIdx.x) >> 4;
    int lane = threadIdx.x & 15;
    if (g >= n) return;
    int start = g * cap;
    int end = start + min(cnt[g], cap);
    float acc = 0.0f;
    for (int base = start; base < end; base += 16) {
        int e = base + lane;
        int r = (e < end) ? eidx[e] : 0;
        int m_cnt = min(16, end - base);
        for (int m = 0; m < m_cnt; m++) {
            int rm = __shfl(r, m, 16);
            acc += h1p[(size_t)rm * F_HID + lane];
        }
    }
    float dc = rsqrtf((float)cnt[g] + 1.0f);
    float v = (acc + h1p[(size_t)g * F_HID + lane]) * dc + b1[lane];
    v = fmaxf(v, 0.0f);
    float t = v * W2[lane];
    t += __shfl_xor(t, 1, 16);
    t += __shfl_xor(t, 2, 16);
    t += __shfl_xor(t, 4, 16);
    t += __shfl_xor(t, 8, 16);
    if (lane == 0) sp[g] = t * dc;
}

__global__ __launch_bounds__(256) void fb_gather2_kernel(const int* __restrict__ cnt,
                                                         const int* __restrict__ eidx,
                                                         const float* __restrict__ sp,
                                                         const float* __restrict__ b2,
                                                         float* __restrict__ out,
                                                         int cap, int n) {
    int g = (blockIdx.x * 256 + threadIdx.x) >> 4;
    int lane = threadIdx.x & 15;
    if (g >= n) return;
    int start = g * cap;
    int end = start + min(cnt[g], cap);
    float acc = 0.0f;
    for (int e = start + lane; e < end; e += 16) {
        acc += sp[eidx[e]];
    }
    acc += __shfl_xor(acc, 1, 16);
    acc += __shfl_xor(acc, 2, 16);
    acc += __shfl_xor(acc, 4, 16);
    acc += __shfl_xor(acc, 8, 16);
    if (lane == 0) {
        float v = (acc + sp[g]) * rsqrtf((float)cnt[g] + 1.0f) + b2[0];
        out[g] = 1.0f / (1.0f + __expf(-v));
    }
}

extern "C" void kernel_launch(void* const* d_in, const int* in_sizes, int n_in,
                              void* d_out, int out_size, void* d_ws, size_t ws_size,
                              hipStream_t stream) {
    const float* x  = (const float*)d_in[0];
    const int*   ei = (const int*)d_in[1];  // [2, E] flat: row then col
    const float* W1 = (const float*)d_in[2];
    const float* b1 = (const float*)d_in[3];
    const float* W2 = (const float*)d_in[4];
    const float* b2 = (const float*)d_in[5];
    float* out = (float*)d_out;

    const int n = in_sizes[0] / F_IN;      // 100000
    const int n_edges = in_sizes[1] / 2;   // 3200000
    const int* row = ei;
    const int* col = ei + n_edges;

    const size_t S = ((size_t)n + 511) & ~(size_t)511;
    const size_t words = ws_size / 4;

    const int B = 256;
    const int gridE = (n_edges + B - 1) / B;
    const int gridN = (n + B - 1) / B;

    const int NB = (n + 255) >> 8;
    int meanB = (NB > 0) ? (n_edges / NB) : 0;
    int capB = ((meanB + meanB / 8 + 1024) + 15) & ~15;  // mean + 12% + slack
    // Layout (words): cnt[S] | cursor[NBMAX] | rowptr[S] | sp[S] |
    //                 h1p(half16)[8S] | ping[NB*capB] | pong[NB*capB]
    size_t need_new = 11 * S + (size_t)NBMAX + 2 * (size_t)NB * (size_t)capB;

    if (n <= 131072 && NB <= NBMAX && capB <= CAPMAX && words >= need_new) {
        int*    cnt    = (int*)d_ws;
        int*    cursor = cnt + S;
        int*    rowptr = cursor + NBMAX;
        float*  sp     = (float*)(rowptr + S);
        __half* h1p    = (__half*)(sp + S);
        int*    ping   = (int*)(sp + S) + 8 * S;
        int*    pong   = ping + (size_t)NB * capB;

        (void)hipMemsetAsync(cursor, 0, NBMAX * sizeof(int), stream);
        int ntiles = (n_edges + PT - 1) / PT;
        int pgrid = min(2048, ntiles);
        partition_kernel<<<pgrid, PPB, 0, stream>>>(row, col, cursor, ping,
                                                    capB, NB, n_edges);
        deg_gemm1_kernel<<<NB, PB, 0, stream>>>(cursor, ping, x, W1, cnt,
                                                rowptr, h1p, capB, n);
        sort_gather1<<<NB, PB, (size_t)capB * sizeof(int), stream>>>(
            cursor, ping, cnt, rowptr, h1p, b1, W2, sp, pong, capB, n);
        int gridG2 = (n * 16 + B - 1) / B;  // 16 lanes per node
        gather2_kernel<<<gridG2, B, 0, stream>>>(rowptr, cnt, pong, sp, b2, out, n);
    } else {
        // FALLBACK (R4): cnt[S] | sp[S] | h1pf[16S] | eidx[n*cap]
        int*   cnt  = (int*)d_ws;
        float* sp   = (float*)(cnt + S);
        float* h1pf = sp + S;
        int*   eidx = (int*)(h1pf + 16 * S);
        size_t tail_words = (words > 18 * S) ? (words - 18 * S) : 0;
        int cap = (int)min((size_t)96, tail_words / (size_t)(n > 0 ? n : 1));
        const int gridG = (n * 16 + B - 1) / B;

        (void)hipMemsetAsync(cnt, 0, (size_t)n * sizeof(int), stream);
        bucket_scatter_kernel<<<gridE, B, 0, stream>>>(row, col, cnt, eidx, cap, n_edges);
        gemm1f_kernel<<<gridN, B, 0, stream>>>(x, W1, cnt, h1pf, n);
        fb_gather1_kernel<<<gridG, B, 0, stream>>>(cnt, eidx, h1pf, b1, W2, sp, cap, n);
        fb_gather2_kernel<<<gridG, B, 0, stream>>>(cnt, eidx, sp, b2, out, cap, n);
    }
}

// Round 11
// 176.539 us; speedup vs baseline: 2.0034x; 1.0180x over previous
//
#include <hip/hip_runtime.h>
#include <hip/hip_fp16.h>
#include <cstdint>

// R23: base = R18 exact (best, 178.3us; R22's PPB=896 was neutral-negative
// -> reverted). One lever: int4-vectorize the three remaining scalar 4B/edge
// global loops (G13): deg_gemm1 phase-A ping read, sort_gather1 ping
// scatter-read, sort_gather1 pong writeout. capB % 16 == 0 -> bucket rows
// 64B-aligned; LDS atomic counts unchanged, only global instr count /4.
// Session evidence: R12 197; R13 610 (latency-chain); R14 296 (global-atomic
// cnt); R15 182.1; R16 189.3; R17 185.8; R18 178.3 BEST; R19 353.7 (coop
// grid-sync -- never); R20 compile-fail; R21 198.5 (NT bypasses L1 merge);
// R22 179.7 (PPB tweak neutral).

#define F_IN 128
#define F_HID 16
#define PB 1024           // partition / deg_gemm1 / sort_gather1 block threads
#define PT 8192           // edges per partition tile
#define NBMAX 512         // max buckets (nodes/256), n <= 131072
#define CAPMAX 15104      // max bucket capacity (LDS B[capB] must fit 64KB)

// ===========================================================================
// Phase 1: counting-sort partition into 256-node dst buckets (R18-exact).
// Packed edge word: r | (c&255)<<17  (needs n <= 2^17). int4 edge loads.
// ===========================================================================
__global__ __launch_bounds__(PB) void partition_kernel(
    const int* __restrict__ row, const int* __restrict__ col,
    int* __restrict__ cursor,        // [NBMAX], zeroed
    int* __restrict__ ping,          // [NB * capB]
    int capB, int NB, int n_edges) {
    __shared__ int sh_hist[NBMAX];
    __shared__ int sh_scan[NBMAX];
    __shared__ int sh_cur[NBMAX];
    __shared__ int sh_base[NBMAX];
    __shared__ int sh_wsum[16];
    __shared__ int sh_packed[PT];
    __shared__ unsigned short sh_bkt[PT];

    int t = threadIdx.x;
    int lane = t & 63;
    int wv = t >> 6;
    int ntiles = (n_edges + PT - 1) / PT;
    bool vec_ok = ((n_edges & 3) == 0);   // col = row + n_edges 16B-aligned

    for (int tile = blockIdx.x; tile < ntiles; tile += gridDim.x) {
        int tbase = tile * PT;
        int tcnt = min(PT, n_edges - tbase);

        if (t < NBMAX) sh_hist[t] = 0;
        __syncthreads();

        int e0 = tbase + t * 8;
        int pk[8], bb[8];
        if (vec_ok && e0 + 8 <= n_edges) {
            int4 a0 = *(const int4*)(row + e0);
            int4 a1 = *(const int4*)(row + e0 + 4);
            int4 c0 = *(const int4*)(col + e0);
            int4 c1 = *(const int4*)(col + e0 + 4);
            int rr[8] = {a0.x, a0.y, a0.z, a0.w, a1.x, a1.y, a1.z, a1.w};
            int cc[8] = {c0.x, c0.y, c0.z, c0.w, c1.x, c1.y, c1.z, c1.w};
#pragma unroll
            for (int k = 0; k < 8; k++) {
                bb[k] = cc[k] >> 8;
                pk[k] = rr[k] | ((cc[k] & 255) << 17);
                atomicAdd(&sh_hist[bb[k]], 1);
            }
        } else {
#pragma unroll
            for (int k = 0; k < 8; k++) {
                int e = e0 + k;
                bb[k] = -1;
                if (e < n_edges) {
                    int r = row[e];
                    int c = col[e];
                    bb[k] = c >> 8;
                    pk[k] = r | ((c & 255) << 17);
                    atomicAdd(&sh_hist[bb[k]], 1);
                }
            }
        }
        __syncthreads();

        // wave-hierarchical inclusive scan of sh_hist[0..511]
        {
            int v = (t < NBMAX) ? sh_hist[t] : 0;
            int incl = v;
#pragma unroll
            for (int off = 1; off < 64; off <<= 1) {
                int u = __shfl_up(incl, off, 64);
                if (lane >= off) incl += u;
            }
            if (lane == 63) sh_wsum[wv] = incl;
            __syncthreads();
            if (t < 16) {
                int s = sh_wsum[t];
#pragma unroll
                for (int off = 1; off < 16; off <<= 1) {
                    int u = __shfl_up(s, off, 16);
                    if (t >= off) s += u;
                }
                sh_wsum[t] = s;
            }
            __syncthreads();
            int wexcl = (wv > 0) ? sh_wsum[wv - 1] : 0;
            if (t < NBMAX) sh_scan[t] = incl + wexcl;
        }
        __syncthreads();

        if (t < NBMAX) {
            int h = sh_hist[t];
            sh_cur[t] = sh_scan[t] - h;
            sh_base[t] = (h > 0 && t < NB) ? atomicAdd(&cursor[t], h) : 0;
        }
        __syncthreads();

        // LDS reorder scatter
#pragma unroll
        for (int k = 0; k < 8; k++) {
            if (bb[k] >= 0) {
                int p = atomicAdd(&sh_cur[bb[k]], 1);
                sh_packed[p] = pk[k];
                sh_bkt[p] = (unsigned short)bb[k];
            }
        }
        __syncthreads();

        // write runs out bucket-contiguously
#pragma unroll
        for (int k = 0; k < 8; k++) {
            int p = t + k * PB;
            if (p < tcnt) {
                int b = sh_bkt[p];
                int off = p - (sh_scan[b] - sh_hist[b]);
                int gp = sh_base[b] + off;
                if (gp < capB) ping[(size_t)b * capB + gp] = sh_packed[p];
            }
        }
        __syncthreads();
    }
}

// ===========================================================================
// Phase 2 (merged, 1024 thr): per-bucket degree histogram (phase A, int4
// ping reads) + gemm1 (phase B, j-split: 4 threads/node, 4 outputs each).
// Block b's node range [256b, 256b+256) == bucket b's range.
// h1p = fp16( (x @ W1) * dinv[node] ), cnt/rowptr written for later kernels.
// ===========================================================================
__global__ __launch_bounds__(PB) void deg_gemm1_kernel(
    const int* __restrict__ cursor, const int* __restrict__ ping,
    const float* __restrict__ x, const float* __restrict__ W1,
    int* __restrict__ cnt, int* __restrict__ rowptr,
    __half* __restrict__ h1p, int capB, int n) {
    __shared__ float sW[F_IN * F_HID];
    __shared__ int hist[256];
    __shared__ int wsum[4];

    int b = blockIdx.x, t = threadIdx.x;
    int lane = t & 63;
    int wv = t >> 6;

    // weight staging (barrier below covers it)
    for (int i = t; i < F_IN * F_HID; i += PB) sW[i] = W1[i];
    if (t < 256) hist[t] = 0;
    __syncthreads();

    // phase A: histogram bucket edges by sub-index, int4 (4 edges/thread/iter)
    int cb = min(cursor[b], capB);
    const int* src = ping + (size_t)b * capB;
    {
        int nv = cb >> 2;                 // int4 count (row 64B-aligned)
        const int4* src4 = (const int4*)src;
        for (int i = t; i < nv; i += PB) {
            int4 v = src4[i];
            atomicAdd(&hist[(v.x >> 17) & 255], 1);
            atomicAdd(&hist[(v.y >> 17) & 255], 1);
            atomicAdd(&hist[(v.z >> 17) & 255], 1);
            atomicAdd(&hist[(v.w >> 17) & 255], 1);
        }
        for (int i = (nv << 2) + t; i < cb; i += PB) {
            atomicAdd(&hist[(src[i] >> 17) & 255], 1);
        }
    }
    __syncthreads();

    // inclusive scan of hist[0..255] (first 4 waves carry data)
    {
        int h = (t < 256) ? hist[t] : 0;
        int incl = h;
#pragma unroll
        for (int off = 1; off < 64; off <<= 1) {
            int u = __shfl_up(incl, off, 64);
            if (lane >= off) incl += u;
        }
        if (t < 256 && lane == 63) wsum[wv] = incl;
        __syncthreads();
        if (t < 4) {
            int s = wsum[t];
#pragma unroll
            for (int off = 1; off < 4; off <<= 1) {
                int u = __shfl_up(s, off, 4);
                if (t >= off) s += u;
            }
            wsum[t] = s;
        }
        __syncthreads();
        if (t < 256) {
            int g = b * 256 + t;
            if (g < n) {
                int wexcl = (wv > 0) ? wsum[wv - 1] : 0;
                cnt[g] = h;
                rowptr[g] = b * capB + (incl + wexcl - h);
            }
        }
    }
    // hist[] untouched by scan -> safe to read below without extra barrier

    // phase B: gemm1, 4 threads per node, 4 output features each
    int sub = t >> 2;
    int node = b * 256 + sub;
    if (node >= n) return;
    int jq = (t & 3) * 4;

    const float4* xr = (const float4*)(x + (size_t)node * F_IN);
    float a0 = 0.0f, a1 = 0.0f, a2 = 0.0f, a3 = 0.0f;

#pragma unroll 4
    for (int k4 = 0; k4 < F_IN / 4; k4++) {
        float4 xv = xr[k4];
        const float* w0 = &sW[(k4 * 4 + 0) * F_HID + jq];
        const float* w1 = &sW[(k4 * 4 + 1) * F_HID + jq];
        const float* w2 = &sW[(k4 * 4 + 2) * F_HID + jq];
        const float* w3 = &sW[(k4 * 4 + 3) * F_HID + jq];
        a0 += xv.x * w0[0] + xv.y * w1[0] + xv.z * w2[0] + xv.w * w3[0];
        a1 += xv.x * w0[1] + xv.y * w1[1] + xv.z * w2[1] + xv.w * w3[1];
        a2 += xv.x * w0[2] + xv.y * w1[2] + xv.z * w2[2] + xv.w * w3[2];
        a3 += xv.x * w0[3] + xv.y * w1[3] + xv.z * w2[3] + xv.w * w3[3];
    }

    float d = rsqrtf((float)hist[sub] + 1.0f);
    __half2 hv[2];
    hv[0] = __floats2half2_rn(a0 * d, a1 * d);
    hv[1] = __floats2half2_rn(a2 * d, a3 * d);
    *(float2*)(h1p + (size_t)node * F_HID + jq) = *(float2*)&hv[0];
}

// ===========================================================================
// Phase 3: fused per-bucket counting sort (LDS) + layer-1 windowed gather.
// int4 ping scatter-read and int4 pong writeout (rows 64B-aligned).
//  pass A: scatter ping -> LDS B[] sorted    pass B: B -> pong (int4)
//  pass C: R12-style windowed gather, 8 lanes/node, edges from LDS
// ===========================================================================
__global__ __launch_bounds__(PB) void sort_gather1(
    const int* __restrict__ cursor, const int* __restrict__ ping,
    const int* __restrict__ cnt, const int* __restrict__ rowptr,
    const __half* __restrict__ h1p, const float* __restrict__ b1,
    const float* __restrict__ W2, float* __restrict__ sp,
    int* __restrict__ pong, int capB, int n) {
    extern __shared__ int B[];        // capB ints (sorted edge srcs)
    __shared__ int s_excl[256];
    __shared__ int s_h[256];
    __shared__ int cur[256];

    int b = blockIdx.x, t = threadIdx.x;

    if (t < 256) {
        int g = b * 256 + t;
        int h = (g < n) ? cnt[g] : 0;
        int excl = (g < n) ? (rowptr[g] - b * capB) : 0;
        s_h[t] = h;
        s_excl[t] = excl;
        cur[t] = excl;
    }
    __syncthreads();

    int cb = min(cursor[b], capB);
    const int* src = ping + (size_t)b * capB;

    // counting scatter into LDS, int4 reads (4 edges/thread/iter)
    {
        int nv = cb >> 2;
        const int4* src4 = (const int4*)src;
        for (int i = t; i < nv; i += PB) {
            int4 v = src4[i];
            int p0 = atomicAdd(&cur[(v.x >> 17) & 255], 1); B[p0] = v.x & 131071;
            int p1 = atomicAdd(&cur[(v.y >> 17) & 255], 1); B[p1] = v.y & 131071;
            int p2 = atomicAdd(&cur[(v.z >> 17) & 255], 1); B[p2] = v.z & 131071;
            int p3 = atomicAdd(&cur[(v.w >> 17) & 255], 1); B[p3] = v.w & 131071;
        }
        for (int i = (nv << 2) + t; i < cb; i += PB) {
            int v = src[i];
            int p = atomicAdd(&cur[(v >> 17) & 255], 1);
            B[p] = v & 131071;
        }
    }
    __syncthreads();

    // pong write-out as int4 (for gather2); drains under the gather below
    {
        int nv = (cb + 3) >> 2;           // round up; B[] slack is harmless,
        int4* pong4 = (int4*)(pong + (size_t)b * capB);   // capB%16==0 pads
        const int4* B4 = (const int4*)B;
        for (int i = t; i < nv; i += PB) {
            pong4[i] = B4[i];
        }
    }

    // windowed gather: 8 lanes per node, 8 independent h1p loads per window
    int l = t & 7;
    for (int j = t >> 3; j < 256; j += (PB >> 3)) {
        int g = b * 256 + j;
        if (g >= n) continue;
        int h = s_h[j];
        int base = s_excl[j];
        int end = base + h;

        float ax = 0.0f, ay = 0.0f;
        for (; base + 8 <= end; base += 8) {
#pragma unroll
            for (int m = 0; m < 8; m++) {
                int rm = B[base + m];
                float2 f = __half22float2(*(const __half2*)(h1p + (size_t)rm * F_HID + 2 * l));
                ax += f.x; ay += f.y;
            }
        }
        for (int m = 0; m < end - base; m++) {
            int rm = B[base + m];
            float2 f = __half22float2(*(const __half2*)(h1p + (size_t)rm * F_HID + 2 * l));
            ax += f.x; ay += f.y;
        }

        float dc = rsqrtf((float)h + 1.0f);
        float2 fs = __half22float2(*(const __half2*)(h1p + (size_t)g * F_HID + 2 * l));
        float v0 = (ax + fs.x) * dc + b1[2 * l];
        float v1 = (ay + fs.y) * dc + b1[2 * l + 1];
        v0 = fmaxf(v0, 0.0f);
        v1 = fmaxf(v1, 0.0f);
        float tt = v0 * W2[2 * l] + v1 * W2[2 * l + 1];  // fused [16,1] GEMM
        tt += __shfl_xor(tt, 1, 8);
        tt += __shfl_xor(tt, 2, 8);
        tt += __shfl_xor(tt, 4, 8);
        if (l == 0) sp[g] = tt * dc;   // pre-scale by src norm for layer 2
    }
}

// ===========================================================================
// Phase 4: layer-2 gather + sigmoid (16 lanes per node) — unchanged R12
// ===========================================================================
__global__ __launch_bounds__(256) void gather2_kernel(const int* __restrict__ rowptr,
                                                      const int* __restrict__ cnt,
                                                      const int* __restrict__ eidx,
                                                      const float* __restrict__ sp,
                                                      const float* __restrict__ b2,
                                                      float* __restrict__ out, int n) {
    int g = (blockIdx.x * 256 + threadIdx.x) >> 4;
    int lane = threadIdx.x & 15;
    if (g >= n) return;
    int start = rowptr[g];
    int end = start + cnt[g];

    float acc = 0.0f;
    for (int e = start + lane; e < end; e += 16) {
        acc += sp[eidx[e]];
    }
    acc += __shfl_xor(acc, 1, 16);
    acc += __shfl_xor(acc, 2, 16);
    acc += __shfl_xor(acc, 4, 16);
    acc += __shfl_xor(acc, 8, 16);
    if (lane == 0) {
        float v = (acc + sp[g]) * rsqrtf((float)cnt[g] + 1.0f) + b2[0];
        out[g] = 1.0f / (1.0f + __expf(-v));
    }
}

// ===========================================================================
// FALLBACK (proven R4): fixed-cap per-node buckets, fp32 h1p
// ===========================================================================
__global__ void bucket_scatter_kernel(const int* __restrict__ row,
                                      const int* __restrict__ col,
                                      int* __restrict__ cnt,
                                      int* __restrict__ eidx,
                                      int cap, int n_edges) {
    int e = blockIdx.x * blockDim.x + threadIdx.x;
    if (e < n_edges) {
        int c = col[e];
        int p = atomicAdd(&cnt[c], 1);
        if (p < cap) eidx[(size_t)c * cap + p] = row[e];
    }
}

__global__ __launch_bounds__(256) void gemm1f_kernel(const float* __restrict__ x,
                                                     const float* __restrict__ W1,
                                                     const int* __restrict__ cnt,
                                                     float* __restrict__ h1p, int n) {
    __shared__ float sW[F_IN * F_HID];
    int tid = threadIdx.x;
    for (int i = tid; i < F_IN * F_HID; i += 256) sW[i] = W1[i];
    __syncthreads();
    int node = blockIdx.x * 256 + tid;
    if (node >= n) return;
    const float4* xr = (const float4*)(x + (size_t)node * F_IN);
    float acc[F_HID];
#pragma unroll
    for (int j = 0; j < F_HID; j++) acc[j] = 0.0f;
#pragma unroll 4
    for (int k4 = 0; k4 < F_IN / 4; k4++) {
        float4 xv = xr[k4];
        const float* w0 = &sW[(k4 * 4 + 0) * F_HID];
        const float* w1 = &sW[(k4 * 4 + 1) * F_HID];
        const float* w2 = &sW[(k4 * 4 + 2) * F_HID];
        const float* w3 = &sW[(k4 * 4 + 3) * F_HID];
#pragma unroll
        for (int j = 0; j < F_HID; j++) {
            acc[j] += xv.x * w0[j] + xv.y * w1[j] + xv.z * w2[j] + xv.w * w3[j];
        }
    }
    float d = rsqrtf((float)cnt[node] + 1.0f);
    float4* outp = (float4*)(h1p + (size_t)node * F_HID);
    outp[0] = make_float4(acc[0] * d, acc[1] * d, acc[2] * d, acc[3] * d);
    outp[1] = make_float4(acc[4] * d, acc[5] * d, acc[6] * d, acc[7] * d);
    outp[2] = make_float4(acc[8] * d, acc[9] * d, acc[10] * d, acc[11] * d);
    outp[3] = make_float4(acc[12] * d, acc[13] * d, acc[14] * d, acc[15] * d);
}

__global__ __launch_bounds__(256) void fb_gather1_kernel(const int* __restrict__ cnt,
                                                         const int* __restrict__ eidx,
                                                         const float* __restrict__ h1p,
                                                         const float* __restrict__ b1,
                                                         const float* __restrict__ W2,
                                                         float* __restrict__ sp,
                                                         int cap, int n) {
    int g = (blockIdx.x * 256 + threadIdx.x) >> 4;
    int lane = threadIdx.x & 15;
    if (g >= n) return;
    int start = g * cap;
    int end = start + min(cnt[g], cap);
    float acc = 0.0f;
    for (int base = start; base < end; base += 16) {
        int e = base + lane;
        int r = (e < end) ? eidx[e] : 0;
        int m_cnt = min(16, end - base);
        for (int m = 0; m < m_cnt; m++) {
            int rm = __shfl(r, m, 16);
            acc += h1p[(size_t)rm * F_HID + lane];
        }
    }
    float dc = rsqrtf((float)cnt[g] + 1.0f);
    float v = (acc + h1p[(size_t)g * F_HID + lane]) * dc + b1[lane];
    v = fmaxf(v, 0.0f);
    float t = v * W2[lane];
    t += __shfl_xor(t, 1, 16);
    t += __shfl_xor(t, 2, 16);
    t += __shfl_xor(t, 4, 16);
    t += __shfl_xor(t, 8, 16);
    if (lane == 0) sp[g] = t * dc;
}

__global__ __launch_bounds__(256) void fb_gather2_kernel(const int* __restrict__ cnt,
                                                         const int* __restrict__ eidx,
                                                         const float* __restrict__ sp,
                                                         const float* __restrict__ b2,
                                                         float* __restrict__ out,
                                                         int cap, int n) {
    int g = (blockIdx.x * 256 + threadIdx.x) >> 4;
    int lane = threadIdx.x & 15;
    if (g >= n) return;
    int start = g * cap;
    int end = start + min(cnt[g], cap);
    float acc = 0.0f;
    for (int e = start + lane; e < end; e += 16) {
        acc += sp[eidx[e]];
    }
    acc += __shfl_xor(acc, 1, 16);
    acc += __shfl_xor(acc, 2, 16);
    acc += __shfl_xor(acc, 4, 16);
    acc += __shfl_xor(acc, 8, 16);
    if (lane == 0) {
        float v = (acc + sp[g]) * rsqrtf((float)cnt[g] + 1.0f) + b2[0];
        out[g] = 1.0f / (1.0f + __expf(-v));
    }
}

extern "C" void kernel_launch(void* const* d_in, const int* in_sizes, int n_in,
                              void* d_out, int out_size, void* d_ws, size_t ws_size,
                              hipStream_t stream) {
    const float* x  = (const float*)d_in[0];
    const int*   ei = (const int*)d_in[1];  // [2, E] flat: row then col
    const float* W1 = (const float*)d_in[2];
    const float* b1 = (const float*)d_in[3];
    const float* W2 = (const float*)d_in[4];
    const float* b2 = (const float*)d_in[5];
    float* out = (float*)d_out;

    const int n = in_sizes[0] / F_IN;      // 100000
    const int n_edges = in_sizes[1] / 2;   // 3200000
    const int* row = ei;
    const int* col = ei + n_edges;

    const size_t S = ((size_t)n + 511) & ~(size_t)511;
    const size_t words = ws_size / 4;

    const int B = 256;
    const int gridE = (n_edges + B - 1) / B;
    const int gridN = (n + B - 1) / B;

    const int NB = (n + 255) >> 8;
    int meanB = (NB > 0) ? (n_edges / NB) : 0;
    int capB = ((meanB + meanB / 8 + 1024) + 15) & ~15;  // mean + 12% + slack
    // Layout (words): cnt[S] | cursor[NBMAX] | rowptr[S] | sp[S] |
    //                 h1p(half16)[8S] | ping[NB*capB] | pong[NB*capB]
    size_t need_new = 11 * S + (size_t)NBMAX + 2 * (size_t)NB * (size_t)capB;

    if (n <= 131072 && NB <= NBMAX && capB <= CAPMAX && words >= need_new) {
        int*    cnt    = (int*)d_ws;
        int*    cursor = cnt + S;
        int*    rowptr = cursor + NBMAX;
        float*  sp     = (float*)(rowptr + S);
        __half* h1p    = (__half*)(sp + S);
        int*    ping   = (int*)(sp + S) + 8 * S;
        int*    pong   = ping + (size_t)NB * capB;

        (void)hipMemsetAsync(cursor, 0, NBMAX * sizeof(int), stream);
        int ntiles = (n_edges + PT - 1) / PT;
        int pgrid = min(2048, ntiles);
        partition_kernel<<<pgrid, PB, 0, stream>>>(row, col, cursor, ping,
                                                   capB, NB, n_edges);
        deg_gemm1_kernel<<<NB, PB, 0, stream>>>(cursor, ping, x, W1, cnt,
                                                rowptr, h1p, capB, n);
        sort_gather1<<<NB, PB, (size_t)capB * sizeof(int), stream>>>(
            cursor, ping, cnt, rowptr, h1p, b1, W2, sp, pong, capB, n);
        int gridG2 = (n * 16 + B - 1) / B;  // 16 lanes per node
        gather2_kernel<<<gridG2, B, 0, stream>>>(rowptr, cnt, pong, sp, b2, out, n);
    } else {
        // FALLBACK (R4): cnt[S] | sp[S] | h1pf[16S] | eidx[n*cap]
        int*   cnt  = (int*)d_ws;
        float* sp   = (float*)(cnt + S);
        float* h1pf = sp + S;
        int*   eidx = (int*)(h1pf + 16 * S);
        size_t tail_words = (words > 18 * S) ? (words - 18 * S) : 0;
        int cap = (int)min((size_t)96, tail_words / (size_t)(n > 0 ? n : 1));
        const int gridG = (n * 16 + B - 1) / B;

        (void)hipMemsetAsync(cnt, 0, (size_t)n * sizeof(int), stream);
        bucket_scatter_kernel<<<gridE, B, 0, stream>>>(row, col, cnt, eidx, cap, n_edges);
        gemm1f_kernel<<<gridN, B, 0, stream>>>(x, W1, cnt, h1pf, n);
        fb_gather1_kernel<<<gridG, B, 0, stream>>>(cnt, eidx, h1pf, b1, W2, sp, cap, n);
        fb_gather2_kernel<<<gridG, B, 0, stream>>>(cnt, eidx, sp, b2, out, cap, n);
    }
}